// Round 2
// baseline (483.950 us; speedup 1.0000x reference)
//
#include <hip/hip_runtime.h>
#include <math.h>

#define N_NODES 50000
#define N_EDGES 500000
#define DIM     128
#define NGRAPH  50
#define NPGC    1000
#define KSEL    500
#define SCAN_B  1024
#define SORT_N  1024

// ---------------- degree / dinv (f64 scoring path) ----------------

__global__ void deg_kernel(const int* __restrict__ dst, int* __restrict__ deg) {
    int e = blockIdx.x * blockDim.x + threadIdx.x;
    if (e < N_EDGES) atomicAdd(&deg[dst[e]], 1);
}

__global__ void dinv_kernel(const int* __restrict__ deg, double* __restrict__ dinv) {
    int i = blockIdx.x * blockDim.x + threadIdx.x;
    if (i < N_NODES) dinv[i] = 1.0 / sqrt((double)(deg[i] + 1));
}

// ---------------- per-node dots: xw_s = x.W_s, sf = x.W_f + b_f ----------------

__global__ void dots_kernel(const float* __restrict__ x, const float* __restrict__ Ws,
                            const float* __restrict__ Wf, const float* __restrict__ bf,
                            double* __restrict__ xw_s, double* __restrict__ sf) {
    int gid  = blockIdx.x * blockDim.x + threadIdx.x;
    int wave = gid >> 6;
    int lane = threadIdx.x & 63;
    if (wave >= N_NODES) return;
    const float* xr = x + (size_t)wave * DIM;
    double x1 = (double)xr[lane], x2 = (double)xr[lane + 64];
    double ps = x1 * (double)Ws[lane] + x2 * (double)Ws[lane + 64];
    double pf = x1 * (double)Wf[lane] + x2 * (double)Wf[lane + 64];
    for (int off = 32; off > 0; off >>= 1) {
        ps += __shfl_down(ps, off, 64);
        pf += __shfl_down(pf, off, 64);
    }
    if (lane == 0) { xw_s[wave] = ps; sf[wave] = pf + (double)bf[0]; }
}

// ---------------- structure-score edge aggregation (f64 atomics) ----------------

__global__ void score_edge_kernel(const int* __restrict__ src, const int* __restrict__ dst,
                                  const double* __restrict__ dinv, const double* __restrict__ xw_s,
                                  double* __restrict__ score_sd) {
    int e = blockIdx.x * blockDim.x + threadIdx.x;
    if (e >= N_EDGES) return;
    int s = src[e], d = dst[e];
    atomicAdd(&score_sd[d], dinv[s] * dinv[d] * xw_s[s]);
}

// ---------------- per-graph top-k: finalize (tanh) + bitonic sort, f64 keys ----------------

__global__ __launch_bounds__(512) void topk_kernel(const double* __restrict__ score_sd,
                                                   const double* __restrict__ dinv,
                                                   const double* __restrict__ xw_s,
                                                   const double* __restrict__ sf,
                                                   const float* __restrict__ bs,
                                                   const int* __restrict__ batch,
                                                   int* __restrict__ perm, int* __restrict__ nodemap,
                                                   float* __restrict__ scoref_sel,
                                                   float* __restrict__ out, long o2, long o3) {
    __shared__ double key[SORT_N];
    __shared__ int    idx[SORT_N];
    int g = blockIdx.x, t = threadIdx.x;
    const double A = 0.6, OMA = 1.0 - 0.6;
    double bsv = (double)bs[0];
    for (int i = t; i < SORT_N; i += 512) {
        if (i < NPGC) {
            int node = g * NPGC + i;
            double di  = dinv[node];
            double tot = score_sd[node] + di * di * xw_s[node] + bsv;  // + self loop + b_s
            key[i] = tanh(A * tot + OMA * sf[node]);
            idx[i] = i;
        } else { key[i] = -1e300; idx[i] = i; }
    }
    __syncthreads();
    for (int size = 2; size <= SORT_N; size <<= 1) {
        for (int stride = size >> 1; stride > 0; stride >>= 1) {
            int a = ((t & ~(stride - 1)) << 1) | (t & (stride - 1));
            int b = a | stride;
            bool descFirst = ((a & size) == 0);
            double ka = key[a], kb = key[b];
            int ia = idx[a], ib = idx[b];
            bool aAfterB = (ka < kb) || (ka == kb && ia > ib);  // stable descending
            if (descFirst ? aAfterB : !aAfterB) {
                key[a] = kb; key[b] = ka;
                idx[a] = ib; idx[b] = ia;
            }
            __syncthreads();
        }
    }
    for (int j = t; j < KSEL; j += 512) {
        int node = g * NPGC + idx[j];
        int pos  = g * KSEL + j;
        perm[pos]        = node;
        nodemap[node]    = pos;
        scoref_sel[pos]  = (float)key[j];
        out[o2 + pos]    = (float)batch[node];  // batch_out
        out[o3 + pos]    = (float)node;         // perm
    }
}

// ---------------- edge compaction: fused flag + block scan ----------------

__global__ __launch_bounds__(SCAN_B) void edge_scan_kernel(const int* __restrict__ src,
                                                           const int* __restrict__ dst,
                                                           const int* __restrict__ nodemap,
                                                           int* __restrict__ epos,
                                                           int* __restrict__ bsums) {
    __shared__ int s[SCAN_B];
    int t = threadIdx.x, g = blockIdx.x * SCAN_B + t;
    int v = 0;
    if (g < N_EDGES) v = (nodemap[src[g]] >= 0 && nodemap[dst[g]] >= 0) ? 1 : 0;
    s[t] = v; __syncthreads();
    for (int off = 1; off < SCAN_B; off <<= 1) {
        int u = (t >= off) ? s[t - off] : 0;
        __syncthreads();
        s[t] += u;
        __syncthreads();
    }
    if (g < N_EDGES) epos[g] = s[t] - v;          // exclusive within block
    if (t == SCAN_B - 1) bsums[blockIdx.x] = s[t];
}

__global__ __launch_bounds__(SCAN_B) void scan_block_kernel(const int* __restrict__ in,
                                                            int* __restrict__ out,
                                                            int* __restrict__ bsums, int n) {
    __shared__ int s[SCAN_B];
    int t = threadIdx.x, g = blockIdx.x * SCAN_B + t;
    int v = (g < n) ? in[g] : 0;
    s[t] = v; __syncthreads();
    for (int off = 1; off < SCAN_B; off <<= 1) {
        int u = (t >= off) ? s[t - off] : 0;
        __syncthreads();
        s[t] += u;
        __syncthreads();
    }
    if (g < n) out[g] = s[t] - v;
    if (t == SCAN_B - 1) bsums[blockIdx.x] = s[t];
}

__global__ __launch_bounds__(SCAN_B) void scan_sums_kernel(int* __restrict__ bsums, int nb) {
    __shared__ int s[SCAN_B];
    int t = threadIdx.x;
    int v = (t < nb) ? bsums[t] : 0;
    s[t] = v; __syncthreads();
    for (int off = 1; off < SCAN_B; off <<= 1) {
        int u = (t >= off) ? s[t - off] : 0;
        __syncthreads();
        s[t] += u;
        __syncthreads();
    }
    if (t < nb) bsums[t] = s[t] - v;              // exclusive
}

__global__ void edge_scatter_kernel(const int* __restrict__ src, const int* __restrict__ dst,
                                    const int* __restrict__ nodemap, const int* __restrict__ epos,
                                    const int* __restrict__ bsums,
                                    float* __restrict__ out_edges, long M) {
    int e = blockIdx.x * blockDim.x + threadIdx.x;
    if (e >= N_EDGES) return;
    int r = nodemap[src[e]], c = nodemap[dst[e]];
    if (r >= 0 && c >= 0) {
        int pos = epos[e] + bsums[e >> 10];
        out_edges[pos]     = (float)r;
        out_edges[M + pos] = (float)c;
    }
}

// ---------------- CSR by dst ----------------

__global__ void csr_fill_kernel(const int* __restrict__ src, const int* __restrict__ dst,
                                const int* __restrict__ rowoff, const int* __restrict__ bsums,
                                int* __restrict__ cursor, int* __restrict__ csr_src) {
    int e = blockIdx.x * blockDim.x + threadIdx.x;
    if (e >= N_EDGES) return;
    int d = dst[e];
    int pos = rowoff[d] + bsums[d >> 10] + atomicAdd(&cursor[d], 1);
    csr_src[pos] = src[e];
}

// ---------------- xw = x @ W_fu (fp32), W staged in 2x32KB LDS halves ----------------
// block: 256 threads, 64 nodes. thread: 8 nodes x 4 channels.
// 32KB LDS -> up to 5 blocks/CU; launch_bounds(256,4) caps VGPR ~128 (16 waves/CU).

__global__ __launch_bounds__(256, 4) void gemm_xw_kernel(const float* __restrict__ x,
                                                         const float* __restrict__ W,
                                                         float* __restrict__ xw) {
    __shared__ float Ws[64 * DIM];          // 32 KB: one k-half of W
    int t = threadIdx.x;
    int ch    = (t & 31) * 4;
    int node0 = blockIdx.x * 64 + (t >> 5) * 8;

    // clamped row pointers (avoid per-iteration bounds branch; dup loads harmless)
    const float* rp[8];
    #pragma unroll
    for (int nn = 0; nn < 8; nn++) {
        int node = node0 + nn;
        rp[nn] = x + (size_t)(node < N_NODES ? node : N_NODES - 1) * DIM;
    }

    float4 acc[8];
    #pragma unroll
    for (int nn = 0; nn < 8; nn++) acc[nn] = make_float4(0.f, 0.f, 0.f, 0.f);

    for (int half = 0; half < 2; half++) {
        { // stage k-half of W: 8192 floats, coalesced float4
            const float4* Wv = (const float4*)(W + half * 64 * DIM);
            float4* Lv = (float4*)Ws;
            for (int i = t; i < 64 * DIM / 4; i += 256) Lv[i] = Wv[i];
        }
        __syncthreads();
        int kg0 = half * 64;
        #pragma unroll 4
        for (int k = 0; k < 64; k += 4) {
            float4 w0 = *(const float4*)&Ws[(k + 0) * DIM + ch];
            float4 w1 = *(const float4*)&Ws[(k + 1) * DIM + ch];
            float4 w2 = *(const float4*)&Ws[(k + 2) * DIM + ch];
            float4 w3 = *(const float4*)&Ws[(k + 3) * DIM + ch];
            #pragma unroll
            for (int nn = 0; nn < 8; nn++) {
                float4 xv = *(const float4*)&rp[nn][kg0 + k];
                acc[nn].x += xv.x * w0.x + xv.y * w1.x + xv.z * w2.x + xv.w * w3.x;
                acc[nn].y += xv.x * w0.y + xv.y * w1.y + xv.z * w2.y + xv.w * w3.y;
                acc[nn].z += xv.x * w0.z + xv.y * w1.z + xv.z * w2.z + xv.w * w3.z;
                acc[nn].w += xv.x * w0.w + xv.y * w1.w + xv.z * w2.w + xv.w * w3.w;
            }
        }
        __syncthreads();
    }
    #pragma unroll
    for (int nn = 0; nn < 8; nn++) {
        int node = node0 + nn;
        if (node < N_NODES) *(float4*)&xw[(size_t)node * DIM + ch] = acc[nn];
    }
}

// ---------------- fusion gather: one wave per selected node ----------------

__global__ void fuse_gather_kernel(const float* __restrict__ xw, const int* __restrict__ perm,
                                   const int* __restrict__ rowoff, const int* __restrict__ bsums,
                                   const int* __restrict__ deg,
                                   const int* __restrict__ csr_src, const double* __restrict__ dinv,
                                   const float* __restrict__ scoref_sel, const float* __restrict__ b_fu,
                                   float* __restrict__ out, long o0, long o4) {
    int gid  = blockIdx.x * blockDim.x + threadIdx.x;
    int wave = gid >> 6;
    int lane = threadIdx.x & 63;
    if (wave >= NGRAPH * KSEL) return;
    int p = perm[wave];
    double dp = dinv[p];
    int c2 = lane * 2;
    float2 v = ((const float2*)(xw + (size_t)p * DIM))[lane];
    float nself = (float)(dp * dp);
    float ax = nself * v.x, ay = nself * v.y;
    int beg = rowoff[p] + bsums[p >> 10], cnt = deg[p];
    for (int e = 0; e < cnt; e++) {
        int s = csr_src[beg + e];
        float nf = (float)(dinv[s] * dp);
        float2 u = ((const float2*)(xw + (size_t)s * DIM))[lane];
        ax += nf * u.x;
        ay += nf * u.y;
    }
    ax += b_fu[c2];
    ay += b_fu[c2 + 1];
    float sc = scoref_sel[wave];
    size_t ro = (size_t)wave * DIM + c2;
    out[o4 + ro]     = ax;        // x_ae
    out[o4 + ro + 1] = ay;
    out[o0 + ro]     = ax * sc;   // x_out
    out[o0 + ro + 1] = ay * sc;
}

// ---------------- host ----------------

extern "C" void kernel_launch(void* const* d_in, const int* in_sizes, int n_in,
                              void* d_out, int out_size, void* d_ws, size_t ws_size,
                              hipStream_t stream) {
    const float* x    = (const float*)d_in[0];
    const int*   ei   = (const int*)d_in[1];
    const int*   src  = ei;
    const int*   dst  = ei + N_EDGES;
    const int*   batch= (const int*)d_in[2];
    const float* W_s  = (const float*)d_in[3];
    const float* b_s  = (const float*)d_in[4];
    const float* W_f  = (const float*)d_in[5];
    const float* b_f  = (const float*)d_in[6];
    const float* W_fu = (const float*)d_in[7];
    const float* b_fu = (const float*)d_in[8];
    float* out = (float*)d_out;

    char* wsp = (char*)d_ws;
    size_t off = 0;
    auto take = [&](size_t bytes) -> char* {
        char* p = wsp + off;
        off = (off + bytes + 255) & ~(size_t)255;
        return p;
    };
    double* dinv       = (double*)take((size_t)N_NODES * 8);
    double* score_sd   = (double*)take((size_t)N_NODES * 8);
    double* xw_s       = (double*)take((size_t)N_NODES * 8);
    double* sf         = (double*)take((size_t)N_NODES * 8);
    float*  scoref_sel = (float*) take((size_t)NGRAPH * KSEL * 4);
    int*    deg        = (int*)   take((size_t)N_NODES * 4);
    int*    perm       = (int*)   take((size_t)NGRAPH * KSEL * 4);
    int*    nodemap    = (int*)   take((size_t)N_NODES * 4);
    int*    rowoff     = (int*)   take((size_t)N_NODES * 4);
    int*    cursor     = (int*)   take((size_t)N_NODES * 4);
    int*    epos       = (int*)   take((size_t)N_EDGES * 4);
    int*    bsumsE     = (int*)   take((size_t)SCAN_B * 4);
    int*    bsumsN     = (int*)   take((size_t)SCAN_B * 4);
    int*    csr_src    = (int*)   take((size_t)N_EDGES * 4);
    float*  xw         = (float*) take((size_t)N_NODES * DIM * 4);

    // output layout: x_out[25000*128] | edge_index_new[2*M] | batch_out | perm | x_ae[25000*128]
    long M  = ((long)out_size - 6450000L) / 2;
    long o1 = 3200000L;
    long o2 = o1 + 2 * M;
    long o3 = o2 + (long)NGRAPH * KSEL;
    long o4 = o3 + (long)NGRAPH * KSEL;

    hipMemsetAsync(deg,      0,    (size_t)N_NODES * 4, stream);
    hipMemsetAsync(score_sd, 0,    (size_t)N_NODES * 8, stream);
    hipMemsetAsync(nodemap,  0xFF, (size_t)N_NODES * 4, stream);  // -1
    hipMemsetAsync(cursor,   0,    (size_t)N_NODES * 4, stream);

    const int TB = 256;
    int gE = (N_EDGES + TB - 1) / TB;
    int gN = (N_NODES + TB - 1) / TB;

    deg_kernel<<<gE, TB, 0, stream>>>(dst, deg);
    dinv_kernel<<<gN, TB, 0, stream>>>(deg, dinv);
    dots_kernel<<<(N_NODES * 64) / TB, TB, 0, stream>>>(x, W_s, W_f, b_f, xw_s, sf);
    score_edge_kernel<<<gE, TB, 0, stream>>>(src, dst, dinv, xw_s, score_sd);

    gemm_xw_kernel<<<(N_NODES + 63) / 64, TB, 0, stream>>>(x, W_fu, xw);

    topk_kernel<<<NGRAPH, 512, 0, stream>>>(score_sd, dinv, xw_s, sf, b_s, batch,
                                            perm, nodemap, scoref_sel, out, o2, o3);

    // edge compaction (order-preserving)
    int nbE = (N_EDGES + SCAN_B - 1) / SCAN_B;   // 489
    edge_scan_kernel<<<nbE, SCAN_B, 0, stream>>>(src, dst, nodemap, epos, bsumsE);
    scan_sums_kernel<<<1, SCAN_B, 0, stream>>>(bsumsE, nbE);
    edge_scatter_kernel<<<gE, TB, 0, stream>>>(src, dst, nodemap, epos, bsumsE, out + o1, M);

    // CSR by dst
    int nbN = (N_NODES + SCAN_B - 1) / SCAN_B;   // 49
    scan_block_kernel<<<nbN, SCAN_B, 0, stream>>>(deg, rowoff, bsumsN, N_NODES);
    scan_sums_kernel<<<1, SCAN_B, 0, stream>>>(bsumsN, nbN);
    csr_fill_kernel<<<gE, TB, 0, stream>>>(src, dst, rowoff, bsumsN, cursor, csr_src);

    fuse_gather_kernel<<<(NGRAPH * KSEL * 64) / TB, TB, 0, stream>>>(
        xw, perm, rowoff, bsumsN, deg, csr_src, dinv, scoref_sel, b_fu, out, 0L, o4);
}

// Round 3
// 306.516 us; speedup vs baseline: 1.5789x; 1.5789x over previous
//
#include <hip/hip_runtime.h>
#include <math.h>

#define N_NODES 50000
#define N_EDGES 500000
#define DIM     128
#define NGRAPH  50
#define NPGC    1000
#define KSEL    500
#define SCAN_B  1024
#define SORT_N  1024
#define NBE     489   // ceil(N_EDGES / SCAN_B)
#define NBN     49    // ceil(N_NODES / SCAN_B)

// ---------------- degree ----------------

__global__ void deg_kernel(const int* __restrict__ dst, int* __restrict__ deg) {
    int e = blockIdx.x * blockDim.x + threadIdx.x;
    if (e < N_EDGES) atomicAdd(&deg[dst[e]], 1);
}

// ---------------- per-node: dinv + dots (xw_s = x.W_s, sf = x.W_f + b_f) ----------------
// one 64-lane wave per node; lane l covers k=l and k=l+64; f64 accumulate.

__global__ void dots_kernel(const float* __restrict__ x, const float* __restrict__ Ws,
                            const float* __restrict__ Wf, const float* __restrict__ bf,
                            const int* __restrict__ deg,
                            double* __restrict__ dinv,
                            double* __restrict__ xw_s, double* __restrict__ sf) {
    int gid  = blockIdx.x * blockDim.x + threadIdx.x;
    int wave = gid >> 6;
    int lane = threadIdx.x & 63;
    if (wave >= N_NODES) return;
    const float* xr = x + (size_t)wave * DIM;
    double x1 = (double)xr[lane], x2 = (double)xr[lane + 64];
    double ps = x1 * (double)Ws[lane] + x2 * (double)Ws[lane + 64];
    double pf = x1 * (double)Wf[lane] + x2 * (double)Wf[lane + 64];
    for (int off = 32; off > 0; off >>= 1) {
        ps += __shfl_down(ps, off, 64);
        pf += __shfl_down(pf, off, 64);
    }
    if (lane == 0) {
        xw_s[wave] = ps;
        sf[wave]   = pf + (double)bf[0];
        dinv[wave] = 1.0 / sqrt((double)(deg[wave] + 1));
    }
}

// ---------------- structure-score edge aggregation (f64 atomics) ----------------

__global__ void score_edge_kernel(const int* __restrict__ src, const int* __restrict__ dst,
                                  const double* __restrict__ dinv, const double* __restrict__ xw_s,
                                  double* __restrict__ score_sd) {
    int e = blockIdx.x * blockDim.x + threadIdx.x;
    if (e >= N_EDGES) return;
    int s = src[e], d = dst[e];
    atomicAdd(&score_sd[d], dinv[s] * dinv[d] * xw_s[s]);
}

// ---------------- per-graph top-k: finalize (tanh) + bitonic sort, f64 keys ----------------

__global__ __launch_bounds__(512) void topk_kernel(const double* __restrict__ score_sd,
                                                   const double* __restrict__ dinv,
                                                   const double* __restrict__ xw_s,
                                                   const double* __restrict__ sf,
                                                   const float* __restrict__ bs,
                                                   const int* __restrict__ batch,
                                                   int* __restrict__ perm, int* __restrict__ nodemap,
                                                   float* __restrict__ scoref_sel,
                                                   float* __restrict__ out, long o2, long o3) {
    __shared__ double key[SORT_N];
    __shared__ int    idx[SORT_N];
    int g = blockIdx.x, t = threadIdx.x;
    const double A = 0.6, OMA = 1.0 - 0.6;
    double bsv = (double)bs[0];
    for (int i = t; i < SORT_N; i += 512) {
        if (i < NPGC) {
            int node = g * NPGC + i;
            double di  = dinv[node];
            double tot = score_sd[node] + di * di * xw_s[node] + bsv;  // + self loop + b_s
            key[i] = tanh(A * tot + OMA * sf[node]);
            idx[i] = i;
        } else { key[i] = -1e300; idx[i] = i; }
    }
    __syncthreads();
    for (int size = 2; size <= SORT_N; size <<= 1) {
        for (int stride = size >> 1; stride > 0; stride >>= 1) {
            int a = ((t & ~(stride - 1)) << 1) | (t & (stride - 1));
            int b = a | stride;
            bool descFirst = ((a & size) == 0);
            double ka = key[a], kb = key[b];
            int ia = idx[a], ib = idx[b];
            bool aAfterB = (ka < kb) || (ka == kb && ia > ib);  // stable descending
            if (descFirst ? aAfterB : !aAfterB) {
                key[a] = kb; key[b] = ka;
                idx[a] = ib; idx[b] = ia;
            }
            __syncthreads();
        }
    }
    for (int j = t; j < KSEL; j += 512) {
        int node = g * NPGC + idx[j];
        int pos  = g * KSEL + j;
        perm[pos]        = node;
        nodemap[node]    = pos;
        scoref_sel[pos]  = (float)key[j];
        out[o2 + pos]    = (float)batch[node];  // batch_out
        out[o3 + pos]    = (float)node;         // perm
    }
}

// ---------------- edge compaction: fused flag + block scan ----------------

__global__ __launch_bounds__(SCAN_B) void edge_scan_kernel(const int* __restrict__ src,
                                                           const int* __restrict__ dst,
                                                           const int* __restrict__ nodemap,
                                                           int* __restrict__ epos,
                                                           int* __restrict__ bsums) {
    __shared__ int s[SCAN_B];
    int t = threadIdx.x, g = blockIdx.x * SCAN_B + t;
    int v = 0;
    if (g < N_EDGES) v = (nodemap[src[g]] >= 0 && nodemap[dst[g]] >= 0) ? 1 : 0;
    s[t] = v; __syncthreads();
    for (int off = 1; off < SCAN_B; off <<= 1) {
        int u = (t >= off) ? s[t - off] : 0;
        __syncthreads();
        s[t] += u;
        __syncthreads();
    }
    if (g < N_EDGES) epos[g] = s[t] - v;          // exclusive within block
    if (t == SCAN_B - 1) bsums[blockIdx.x] = s[t];
}

__global__ __launch_bounds__(SCAN_B) void scan_block_kernel(const int* __restrict__ in,
                                                            int* __restrict__ out,
                                                            int* __restrict__ bsums, int n) {
    __shared__ int s[SCAN_B];
    int t = threadIdx.x, g = blockIdx.x * SCAN_B + t;
    int v = (g < n) ? in[g] : 0;
    s[t] = v; __syncthreads();
    for (int off = 1; off < SCAN_B; off <<= 1) {
        int u = (t >= off) ? s[t - off] : 0;
        __syncthreads();
        s[t] += u;
        __syncthreads();
    }
    if (g < n) out[g] = s[t] - v;
    if (t == SCAN_B - 1) bsums[blockIdx.x] = s[t];
}

// block 0: scan bsumsE (NBE entries); block 1: scan bsumsN (NBN entries)
__global__ __launch_bounds__(SCAN_B) void scan_sums2_kernel(int* __restrict__ bsumsE,
                                                            int* __restrict__ bsumsN) {
    __shared__ int s[SCAN_B];
    int* b  = (blockIdx.x == 0) ? bsumsE : bsumsN;
    int  nb = (blockIdx.x == 0) ? NBE : NBN;
    int t = threadIdx.x;
    int v = (t < nb) ? b[t] : 0;
    s[t] = v; __syncthreads();
    for (int off = 1; off < SCAN_B; off <<= 1) {
        int u = (t >= off) ? s[t - off] : 0;
        __syncthreads();
        s[t] += u;
        __syncthreads();
    }
    if (t < nb) b[t] = s[t] - v;                  // exclusive
}

// ---------------- fused: edge scatter (remap) + CSR fill ----------------

__global__ void scatter_csr_kernel(const int* __restrict__ src, const int* __restrict__ dst,
                                   const int* __restrict__ nodemap, const int* __restrict__ epos,
                                   const int* __restrict__ bsumsE,
                                   const int* __restrict__ rowoff, const int* __restrict__ bsumsN,
                                   int* __restrict__ cursor, int* __restrict__ csr_src,
                                   float* __restrict__ out_edges, long M) {
    int e = blockIdx.x * blockDim.x + threadIdx.x;
    if (e >= N_EDGES) return;
    int sn = src[e], d = dst[e];
    // CSR fill (by dst)
    int pos = rowoff[d] + bsumsN[d >> 10] + atomicAdd(&cursor[d], 1);
    csr_src[pos] = sn;
    // edge compaction
    int r = nodemap[sn], c = nodemap[d];
    if (r >= 0 && c >= 0) {
        int ep = epos[e] + bsumsE[e >> 10];
        out_edges[ep]     = (float)r;
        out_edges[M + ep] = (float)c;
    }
}

// ---------------- xw = x @ W_fu (fp32), W staged in 2x32KB LDS halves ----------------
// block: 256 threads, 32 nodes. thread: 4 nodes x 4 channels.
// 32KB LDS -> 5 blocks/CU; grid 1563 -> ~6 blocks/CU available. No VGPR cap (spill
// disaster at 64 VGPRs in round 2: 830 MB scratch traffic).

__global__ __launch_bounds__(256) void gemm_xw_kernel(const float* __restrict__ x,
                                                      const float* __restrict__ W,
                                                      float* __restrict__ xw) {
    __shared__ float Ws[64 * DIM];          // 32 KB: one k-half of W
    int t = threadIdx.x;
    int ch    = (t & 31) * 4;
    int node0 = blockIdx.x * 32 + (t >> 5) * 4;

    const float* rp[4];
    #pragma unroll
    for (int nn = 0; nn < 4; nn++) {
        int node = node0 + nn;
        rp[nn] = x + (size_t)(node < N_NODES ? node : N_NODES - 1) * DIM;
    }

    float4 acc[4];
    #pragma unroll
    for (int nn = 0; nn < 4; nn++) acc[nn] = make_float4(0.f, 0.f, 0.f, 0.f);

    for (int half = 0; half < 2; half++) {
        { // stage k-half of W: 8192 floats, coalesced float4
            const float4* Wv = (const float4*)(W + half * 64 * DIM);
            float4* Lv = (float4*)Ws;
            for (int i = t; i < 64 * DIM / 4; i += 256) Lv[i] = Wv[i];
        }
        __syncthreads();
        int kg0 = half * 64;
        #pragma unroll
        for (int k = 0; k < 64; k += 4) {
            float4 w0 = *(const float4*)&Ws[(k + 0) * DIM + ch];
            float4 w1 = *(const float4*)&Ws[(k + 1) * DIM + ch];
            float4 w2 = *(const float4*)&Ws[(k + 2) * DIM + ch];
            float4 w3 = *(const float4*)&Ws[(k + 3) * DIM + ch];
            #pragma unroll
            for (int nn = 0; nn < 4; nn++) {
                float4 xv = *(const float4*)&rp[nn][kg0 + k];
                acc[nn].x += xv.x * w0.x + xv.y * w1.x + xv.z * w2.x + xv.w * w3.x;
                acc[nn].y += xv.x * w0.y + xv.y * w1.y + xv.z * w2.y + xv.w * w3.y;
                acc[nn].z += xv.x * w0.z + xv.y * w1.z + xv.z * w2.z + xv.w * w3.z;
                acc[nn].w += xv.x * w0.w + xv.y * w1.w + xv.z * w2.w + xv.w * w3.w;
            }
        }
        __syncthreads();
    }
    #pragma unroll
    for (int nn = 0; nn < 4; nn++) {
        int node = node0 + nn;
        if (node < N_NODES) *(float4*)&xw[(size_t)node * DIM + ch] = acc[nn];
    }
}

// ---------------- fusion gather: one wave per selected node ----------------

__global__ void fuse_gather_kernel(const float* __restrict__ xw, const int* __restrict__ perm,
                                   const int* __restrict__ rowoff, const int* __restrict__ bsums,
                                   const int* __restrict__ deg,
                                   const int* __restrict__ csr_src, const double* __restrict__ dinv,
                                   const float* __restrict__ scoref_sel, const float* __restrict__ b_fu,
                                   float* __restrict__ out, long o0, long o4) {
    int gid  = blockIdx.x * blockDim.x + threadIdx.x;
    int wave = gid >> 6;
    int lane = threadIdx.x & 63;
    if (wave >= NGRAPH * KSEL) return;
    int p = perm[wave];
    double dp = dinv[p];
    int c2 = lane * 2;
    float2 v = ((const float2*)(xw + (size_t)p * DIM))[lane];
    float nself = (float)(dp * dp);
    float ax = nself * v.x, ay = nself * v.y;
    int beg = rowoff[p] + bsums[p >> 10], cnt = deg[p];
    for (int e = 0; e < cnt; e++) {
        int s = csr_src[beg + e];
        float nf = (float)(dinv[s] * dp);
        float2 u = ((const float2*)(xw + (size_t)s * DIM))[lane];
        ax += nf * u.x;
        ay += nf * u.y;
    }
    ax += b_fu[c2];
    ay += b_fu[c2 + 1];
    float sc = scoref_sel[wave];
    size_t ro = (size_t)wave * DIM + c2;
    out[o4 + ro]     = ax;        // x_ae
    out[o4 + ro + 1] = ay;
    out[o0 + ro]     = ax * sc;   // x_out
    out[o0 + ro + 1] = ay * sc;
}

// ---------------- host ----------------

extern "C" void kernel_launch(void* const* d_in, const int* in_sizes, int n_in,
                              void* d_out, int out_size, void* d_ws, size_t ws_size,
                              hipStream_t stream) {
    const float* x    = (const float*)d_in[0];
    const int*   ei   = (const int*)d_in[1];
    const int*   src  = ei;
    const int*   dst  = ei + N_EDGES;
    const int*   batch= (const int*)d_in[2];
    const float* W_s  = (const float*)d_in[3];
    const float* b_s  = (const float*)d_in[4];
    const float* W_f  = (const float*)d_in[5];
    const float* b_f  = (const float*)d_in[6];
    const float* W_fu = (const float*)d_in[7];
    const float* b_fu = (const float*)d_in[8];
    float* out = (float*)d_out;

    char* wsp = (char*)d_ws;
    size_t off = 0;
    auto take = [&](size_t bytes) -> char* {
        char* p = wsp + off;
        off = (off + bytes + 255) & ~(size_t)255;
        return p;
    };
    // zero-cluster: score_sd | deg | cursor are contiguous -> one memset
    char*   zbase      = wsp;
    double* score_sd   = (double*)take((size_t)N_NODES * 8);
    int*    deg        = (int*)   take((size_t)N_NODES * 4);
    int*    cursor     = (int*)   take((size_t)N_NODES * 4);
    size_t  zbytes     = off;
    double* dinv       = (double*)take((size_t)N_NODES * 8);
    double* xw_s       = (double*)take((size_t)N_NODES * 8);
    double* sf         = (double*)take((size_t)N_NODES * 8);
    float*  scoref_sel = (float*) take((size_t)NGRAPH * KSEL * 4);
    int*    perm       = (int*)   take((size_t)NGRAPH * KSEL * 4);
    int*    nodemap    = (int*)   take((size_t)N_NODES * 4);
    int*    rowoff     = (int*)   take((size_t)N_NODES * 4);
    int*    epos       = (int*)   take((size_t)N_EDGES * 4);
    int*    bsumsE     = (int*)   take((size_t)SCAN_B * 4);
    int*    bsumsN     = (int*)   take((size_t)SCAN_B * 4);
    int*    csr_src    = (int*)   take((size_t)N_EDGES * 4);
    float*  xw         = (float*) take((size_t)N_NODES * DIM * 4);

    // output layout: x_out[25000*128] | edge_index_new[2*M] | batch_out | perm | x_ae[25000*128]
    long M  = ((long)out_size - 6450000L) / 2;
    long o1 = 3200000L;
    long o2 = o1 + 2 * M;
    long o3 = o2 + (long)NGRAPH * KSEL;
    long o4 = o3 + (long)NGRAPH * KSEL;

    hipMemsetAsync(zbase,   0,    zbytes, stream);
    hipMemsetAsync(nodemap, 0xFF, (size_t)N_NODES * 4, stream);  // -1

    const int TB = 256;
    int gE = (N_EDGES + TB - 1) / TB;

    deg_kernel<<<gE, TB, 0, stream>>>(dst, deg);
    scan_block_kernel<<<NBN, SCAN_B, 0, stream>>>(deg, rowoff, bsumsN, N_NODES);  // needs deg only
    dots_kernel<<<(N_NODES * 64) / TB, TB, 0, stream>>>(x, W_s, W_f, b_f, deg, dinv, xw_s, sf);
    score_edge_kernel<<<gE, TB, 0, stream>>>(src, dst, dinv, xw_s, score_sd);

    gemm_xw_kernel<<<(N_NODES + 31) / 32, TB, 0, stream>>>(x, W_fu, xw);

    topk_kernel<<<NGRAPH, 512, 0, stream>>>(score_sd, dinv, xw_s, sf, b_s, batch,
                                            perm, nodemap, scoref_sel, out, o2, o3);

    edge_scan_kernel<<<NBE, SCAN_B, 0, stream>>>(src, dst, nodemap, epos, bsumsE);
    scan_sums2_kernel<<<2, SCAN_B, 0, stream>>>(bsumsE, bsumsN);
    scatter_csr_kernel<<<gE, TB, 0, stream>>>(src, dst, nodemap, epos, bsumsE,
                                              rowoff, bsumsN, cursor, csr_src, out + o1, M);

    fuse_gather_kernel<<<(NGRAPH * KSEL * 64) / TB, TB, 0, stream>>>(
        xw, perm, rowoff, bsumsN, deg, csr_src, dinv, scoref_sel, b_fu, out, 0L, o4);
}

// Round 4
// 273.405 us; speedup vs baseline: 1.7701x; 1.1211x over previous
//
#include <hip/hip_runtime.h>
#include <math.h>

#define N_NODES 50000
#define N_EDGES 500000
#define DIM     128
#define NGRAPH  50
#define NPGC    1000
#define KSEL    500
#define SORT_N  1024
#define NBE     489   // ceil(N_EDGES / 1024)
#define NBN     49    // ceil(N_NODES / 1024)

// ---------------- degree ----------------

__global__ void deg_kernel(const int* __restrict__ dst, int* __restrict__ deg) {
    int e = blockIdx.x * blockDim.x + threadIdx.x;
    if (e < N_EDGES) atomicAdd(&deg[dst[e]], 1);
}

// ---------------- per-node: dinv (f64+f32) + dots (xw_s = x.W_s, sf = x.W_f + b_f) ----------------
// one 64-lane wave per node; lane l covers k=l and k=l+64; f64 accumulate (ranking path).

__global__ void dots_kernel(const float* __restrict__ x, const float* __restrict__ Ws,
                            const float* __restrict__ Wf, const float* __restrict__ bf,
                            const int* __restrict__ deg,
                            double* __restrict__ dinv, float* __restrict__ dinvf,
                            double* __restrict__ xw_s, double* __restrict__ sf) {
    int gid  = blockIdx.x * blockDim.x + threadIdx.x;
    int wave = gid >> 6;
    int lane = threadIdx.x & 63;
    if (wave >= N_NODES) return;
    const float* xr = x + (size_t)wave * DIM;
    double x1 = (double)xr[lane], x2 = (double)xr[lane + 64];
    double ps = x1 * (double)Ws[lane] + x2 * (double)Ws[lane + 64];
    double pf = x1 * (double)Wf[lane] + x2 * (double)Wf[lane + 64];
    for (int off = 32; off > 0; off >>= 1) {
        ps += __shfl_down(ps, off, 64);
        pf += __shfl_down(pf, off, 64);
    }
    if (lane == 0) {
        double di = 1.0 / sqrt((double)(deg[wave] + 1));
        xw_s[wave]  = ps;
        sf[wave]    = pf + (double)bf[0];
        dinv[wave]  = di;
        dinvf[wave] = (float)di;
    }
}

// ---------------- structure-score edge aggregation (f64 atomics, ranking path) ----------------

__global__ void score_edge_kernel(const int* __restrict__ src, const int* __restrict__ dst,
                                  const double* __restrict__ dinv, const double* __restrict__ xw_s,
                                  double* __restrict__ score_sd) {
    int e = blockIdx.x * blockDim.x + threadIdx.x;
    if (e >= N_EDGES) return;
    int s = src[e], d = dst[e];
    atomicAdd(&score_sd[d], dinv[s] * dinv[d] * xw_s[s]);
}

// ---------------- per-graph top-k: finalize (tanh) + bitonic sort, f64 keys ----------------

__global__ __launch_bounds__(512) void topk_kernel(const double* __restrict__ score_sd,
                                                   const double* __restrict__ dinv,
                                                   const double* __restrict__ xw_s,
                                                   const double* __restrict__ sf,
                                                   const float* __restrict__ bs,
                                                   const int* __restrict__ batch,
                                                   int* __restrict__ perm, int* __restrict__ nodemap,
                                                   float* __restrict__ scoref_sel,
                                                   float* __restrict__ out, long o2, long o3) {
    __shared__ double key[SORT_N];
    __shared__ int    idx[SORT_N];
    int g = blockIdx.x, t = threadIdx.x;
    const double A = 0.6, OMA = 1.0 - 0.6;
    double bsv = (double)bs[0];
    for (int i = t; i < SORT_N; i += 512) {
        if (i < NPGC) {
            int node = g * NPGC + i;
            double di  = dinv[node];
            double tot = score_sd[node] + di * di * xw_s[node] + bsv;  // + self loop + b_s
            key[i] = tanh(A * tot + OMA * sf[node]);
            idx[i] = i;
        } else { key[i] = -1e300; idx[i] = i; }
    }
    __syncthreads();
    for (int size = 2; size <= SORT_N; size <<= 1) {
        for (int stride = size >> 1; stride > 0; stride >>= 1) {
            int a = ((t & ~(stride - 1)) << 1) | (t & (stride - 1));
            int b = a | stride;
            bool descFirst = ((a & size) == 0);
            double ka = key[a], kb = key[b];
            int ia = idx[a], ib = idx[b];
            bool aAfterB = (ka < kb) || (ka == kb && ia > ib);  // stable descending
            if (descFirst ? aAfterB : !aAfterB) {
                key[a] = kb; key[b] = ka;
                idx[a] = ib; idx[b] = ia;
            }
            __syncthreads();
        }
    }
    for (int j = t; j < KSEL; j += 512) {
        int node = g * NPGC + idx[j];
        int pos  = g * KSEL + j;
        perm[pos]        = node;
        nodemap[node]    = pos;
        scoref_sel[pos]  = (float)key[j];
        out[o2 + pos]    = (float)batch[node];  // batch_out
        out[o3 + pos]    = (float)node;         // perm
    }
}

// ---------------- wave-shuffle block scan (1024 threads, 2 barriers) ----------------

__device__ __forceinline__ int block_incl_scan(int v, int t, int* wsum) {
    int lane = t & 63, wid = t >> 6;
    int sc = v;
    #pragma unroll
    for (int off = 1; off < 64; off <<= 1) {
        int u = __shfl_up(sc, off, 64);
        if (lane >= off) sc += u;
    }
    if (lane == 63) wsum[wid] = sc;
    __syncthreads();
    if (wid == 0) {
        int w = (lane < 16) ? wsum[lane] : 0;
        int ws = w;
        #pragma unroll
        for (int off = 1; off < 16; off <<= 1) {
            int u = __shfl_up(ws, off, 64);
            if (lane >= off) ws += u;
        }
        if (lane < 16) wsum[lane] = ws - w;   // exclusive wave offsets
    }
    __syncthreads();
    return sc + wsum[wid];
}

// flags computed inline + block scan of 1024 edges
__global__ __launch_bounds__(1024) void edge_scan_kernel(const int* __restrict__ src,
                                                         const int* __restrict__ dst,
                                                         const int* __restrict__ nodemap,
                                                         int* __restrict__ epos,
                                                         int* __restrict__ bsums) {
    __shared__ int wsum[16];
    int t = threadIdx.x, g = blockIdx.x * 1024 + t;
    int v = 0;
    if (g < N_EDGES) v = (nodemap[src[g]] >= 0 && nodemap[dst[g]] >= 0) ? 1 : 0;
    int incl = block_incl_scan(v, t, wsum);
    if (g < N_EDGES) epos[g] = incl - v;          // exclusive within block
    if (t == 1023) bsums[blockIdx.x] = incl;
}

__global__ __launch_bounds__(1024) void scan_block_kernel(const int* __restrict__ in,
                                                          int* __restrict__ out,
                                                          int* __restrict__ bsums, int n) {
    __shared__ int wsum[16];
    int t = threadIdx.x, g = blockIdx.x * 1024 + t;
    int v = (g < n) ? in[g] : 0;
    int incl = block_incl_scan(v, t, wsum);
    if (g < n) out[g] = incl - v;
    if (t == 1023) bsums[blockIdx.x] = incl;
}

// block 0: scan bsumsE (NBE entries); block 1: scan bsumsN (NBN entries)
__global__ __launch_bounds__(1024) void scan_sums2_kernel(int* __restrict__ bsumsE,
                                                          int* __restrict__ bsumsN) {
    __shared__ int wsum[16];
    int* b  = (blockIdx.x == 0) ? bsumsE : bsumsN;
    int  nb = (blockIdx.x == 0) ? NBE : NBN;
    int t = threadIdx.x;
    int v = (t < nb) ? b[t] : 0;
    int incl = block_incl_scan(v, t, wsum);
    if (t < nb) b[t] = incl - v;                  // exclusive
}

// ---------------- fused: edge scatter (remap) + CSR fill (with precomputed edge norm) ----------------

__global__ void scatter_csr_kernel(const int* __restrict__ src, const int* __restrict__ dst,
                                   const int* __restrict__ nodemap, const int* __restrict__ epos,
                                   const int* __restrict__ bsumsE,
                                   const int* __restrict__ rowoff, const int* __restrict__ bsumsN,
                                   const float* __restrict__ dinvf,
                                   int* __restrict__ cursor, int2* __restrict__ csr,
                                   float* __restrict__ out_edges, long M) {
    int e = blockIdx.x * blockDim.x + threadIdx.x;
    if (e >= N_EDGES) return;
    int sn = src[e], d = dst[e];
    // CSR fill (by dst), norm packed alongside src id
    int pos = rowoff[d] + bsumsN[d >> 10] + atomicAdd(&cursor[d], 1);
    csr[pos] = make_int2(sn, __float_as_int(dinvf[sn] * dinvf[d]));
    // edge compaction
    int r = nodemap[sn], c = nodemap[d];
    if (r >= 0 && c >= 0) {
        int ep = epos[e] + bsumsE[e >> 10];
        out_edges[ep]     = (float)r;
        out_edges[M + ep] = (float)c;
    }
}

// ---------------- xw = x @ W_fu (fp32), W-half + x-tile both in LDS ----------------
// block: 256 threads -> 128 nodes x 128 ch. thread: 8 nodes x 8 ch (two float4 col blocks).
// LDS = 32KB W-half + 32KB x-half (XOR-swizzled float4 cols, conflict-free reads) = 64KB
// -> 2 blocks/CU; grid 391 <= 512 resident slots -> single pass. Each x element hits
// global exactly once per block (round-3 version issued 32x-redundant VMEM: 24% VALU, 9% occ).

__global__ __launch_bounds__(256) void gemm_xw_kernel(const float* __restrict__ x,
                                                      const float* __restrict__ W,
                                                      float* __restrict__ xw) {
    __shared__ float Wt[64 * DIM];     // [k][ch], k-half
    __shared__ float Xt[128 * 64];     // [node][k-half], float4 col c stored at c^(node&15)
    int t  = threadIdx.x;
    int cg = t & 15;                   // ch cols cg*4 and cg*4+64
    int ng = t >> 4;                   // nodes ng + 16*nn
    int node_base = blockIdx.x * 128;

    float4 acc[8][2];
    #pragma unroll
    for (int nn = 0; nn < 8; nn++) {
        acc[nn][0] = make_float4(0.f, 0.f, 0.f, 0.f);
        acc[nn][1] = make_float4(0.f, 0.f, 0.f, 0.f);
    }

    for (int half = 0; half < 2; half++) {
        const float4* Wg = (const float4*)(W + half * 64 * DIM);
        float4* Wl = (float4*)Wt;
        #pragma unroll
        for (int i = 0; i < 8; i++) {
            int f = t + i * 256;                   // 0..2047
            Wl[f] = Wg[f];
        }
        #pragma unroll
        for (int i = 0; i < 8; i++) {
            int f = t + i * 256;                   // 0..2047
            int row = f >> 4, col = f & 15;
            int node = node_base + row;
            float4 v = make_float4(0.f, 0.f, 0.f, 0.f);
            if (node < N_NODES) v = *(const float4*)&x[(size_t)node * DIM + half * 64 + col * 4];
            *(float4*)&Xt[(row << 6) + ((col ^ (row & 15)) << 2)] = v;
        }
        __syncthreads();
        #pragma unroll 2
        for (int kc = 0; kc < 16; kc++) {          // 4-k chunks
            int k = kc << 2;
            float4 wa[4], wb[4];
            #pragma unroll
            for (int kk = 0; kk < 4; kk++) {
                wa[kk] = *(const float4*)&Wt[(k + kk) * DIM + (cg << 2)];
                wb[kk] = *(const float4*)&Wt[(k + kk) * DIM + (cg << 2) + 64];
            }
            int csw = (kc ^ ng) << 2;              // swizzled col (row&15 == ng for all nn)
            #pragma unroll
            for (int nn = 0; nn < 8; nn++) {
                float4 xv = *(const float4*)&Xt[((ng + (nn << 4)) << 6) + csw];
                acc[nn][0].x += xv.x * wa[0].x + xv.y * wa[1].x + xv.z * wa[2].x + xv.w * wa[3].x;
                acc[nn][0].y += xv.x * wa[0].y + xv.y * wa[1].y + xv.z * wa[2].y + xv.w * wa[3].y;
                acc[nn][0].z += xv.x * wa[0].z + xv.y * wa[1].z + xv.z * wa[2].z + xv.w * wa[3].z;
                acc[nn][0].w += xv.x * wa[0].w + xv.y * wa[1].w + xv.z * wa[2].w + xv.w * wa[3].w;
                acc[nn][1].x += xv.x * wb[0].x + xv.y * wb[1].x + xv.z * wb[2].x + xv.w * wb[3].x;
                acc[nn][1].y += xv.x * wb[0].y + xv.y * wb[1].y + xv.z * wb[2].y + xv.w * wb[3].y;
                acc[nn][1].z += xv.x * wb[0].z + xv.y * wb[1].z + xv.z * wb[2].z + xv.w * wb[3].z;
                acc[nn][1].w += xv.x * wb[0].w + xv.y * wb[1].w + xv.z * wb[2].w + xv.w * wb[3].w;
            }
        }
        __syncthreads();
    }
    #pragma unroll
    for (int nn = 0; nn < 8; nn++) {
        int node = node_base + ng + (nn << 4);
        if (node < N_NODES) {
            *(float4*)&xw[(size_t)node * DIM + (cg << 2)]      = acc[nn][0];
            *(float4*)&xw[(size_t)node * DIM + (cg << 2) + 64] = acc[nn][1];
        }
    }
}

// ---------------- fusion gather: one wave per selected node, 2-way ILP ----------------

__global__ void fuse_gather_kernel(const float* __restrict__ xw, const int* __restrict__ perm,
                                   const int* __restrict__ rowoff, const int* __restrict__ bsums,
                                   const int* __restrict__ deg, const int2* __restrict__ csr,
                                   const float* __restrict__ dinvf,
                                   const float* __restrict__ scoref_sel, const float* __restrict__ b_fu,
                                   float* __restrict__ out, long o4) {
    int gid  = blockIdx.x * blockDim.x + threadIdx.x;
    int wave = gid >> 6;
    int lane = threadIdx.x & 63;
    if (wave >= NGRAPH * KSEL) return;
    int p = perm[wave];
    float dpf = dinvf[p];
    int c2 = lane * 2;
    float2 v = ((const float2*)(xw + (size_t)p * DIM))[lane];
    float nself = dpf * dpf;
    float ax = nself * v.x, ay = nself * v.y;
    int beg = rowoff[p] + bsums[p >> 10], cnt = deg[p];
    int i = 0;
    for (; i + 2 <= cnt; i += 2) {
        int2 e0 = csr[beg + i];
        int2 e1 = csr[beg + i + 1];
        float2 u0 = ((const float2*)(xw + (size_t)e0.x * DIM))[lane];
        float2 u1 = ((const float2*)(xw + (size_t)e1.x * DIM))[lane];
        float n0 = __int_as_float(e0.y), n1 = __int_as_float(e1.y);
        ax += n0 * u0.x; ay += n0 * u0.y;
        ax += n1 * u1.x; ay += n1 * u1.y;
    }
    if (i < cnt) {
        int2 e0 = csr[beg + i];
        float2 u0 = ((const float2*)(xw + (size_t)e0.x * DIM))[lane];
        float n0 = __int_as_float(e0.y);
        ax += n0 * u0.x; ay += n0 * u0.y;
    }
    ax += b_fu[c2];
    ay += b_fu[c2 + 1];
    float sc = scoref_sel[wave];
    size_t ro = (size_t)wave * DIM + c2;
    out[o4 + ro]     = ax;        // x_ae
    out[o4 + ro + 1] = ay;
    out[ro]          = ax * sc;   // x_out
    out[ro + 1]      = ay * sc;
}

// ---------------- host ----------------

extern "C" void kernel_launch(void* const* d_in, const int* in_sizes, int n_in,
                              void* d_out, int out_size, void* d_ws, size_t ws_size,
                              hipStream_t stream) {
    const float* x    = (const float*)d_in[0];
    const int*   ei   = (const int*)d_in[1];
    const int*   src  = ei;
    const int*   dst  = ei + N_EDGES;
    const int*   batch= (const int*)d_in[2];
    const float* W_s  = (const float*)d_in[3];
    const float* b_s  = (const float*)d_in[4];
    const float* W_f  = (const float*)d_in[5];
    const float* b_f  = (const float*)d_in[6];
    const float* W_fu = (const float*)d_in[7];
    const float* b_fu = (const float*)d_in[8];
    float* out = (float*)d_out;

    char* wsp = (char*)d_ws;
    size_t off = 0;
    auto take = [&](size_t bytes) -> char* {
        char* p = wsp + off;
        off = (off + bytes + 255) & ~(size_t)255;
        return p;
    };
    // zero-cluster: score_sd | deg | cursor contiguous -> one memset
    char*   zbase      = wsp;
    double* score_sd   = (double*)take((size_t)N_NODES * 8);
    int*    deg        = (int*)   take((size_t)N_NODES * 4);
    int*    cursor     = (int*)   take((size_t)N_NODES * 4);
    size_t  zbytes     = off;
    double* dinv       = (double*)take((size_t)N_NODES * 8);
    double* xw_s       = (double*)take((size_t)N_NODES * 8);
    double* sf         = (double*)take((size_t)N_NODES * 8);
    float*  dinvf      = (float*) take((size_t)N_NODES * 4);
    float*  scoref_sel = (float*) take((size_t)NGRAPH * KSEL * 4);
    int*    perm       = (int*)   take((size_t)NGRAPH * KSEL * 4);
    int*    nodemap    = (int*)   take((size_t)N_NODES * 4);
    int*    rowoff     = (int*)   take((size_t)N_NODES * 4);
    int*    epos       = (int*)   take((size_t)N_EDGES * 4);
    int*    bsumsE     = (int*)   take((size_t)1024 * 4);
    int*    bsumsN     = (int*)   take((size_t)1024 * 4);
    int2*   csr        = (int2*)  take((size_t)N_EDGES * 8);
    float*  xw         = (float*) take((size_t)N_NODES * DIM * 4);

    // output layout: x_out[25000*128] | edge_index_new[2*M] | batch_out | perm | x_ae[25000*128]
    long M  = ((long)out_size - 6450000L) / 2;
    long o1 = 3200000L;
    long o2 = o1 + 2 * M;
    long o3 = o2 + (long)NGRAPH * KSEL;
    long o4 = o3 + (long)NGRAPH * KSEL;

    hipMemsetAsync(zbase,   0,    zbytes, stream);
    hipMemsetAsync(nodemap, 0xFF, (size_t)N_NODES * 4, stream);  // -1

    const int TB = 256;
    int gE = (N_EDGES + TB - 1) / TB;

    deg_kernel<<<gE, TB, 0, stream>>>(dst, deg);
    scan_block_kernel<<<NBN, 1024, 0, stream>>>(deg, rowoff, bsumsN, N_NODES);
    dots_kernel<<<(N_NODES * 64) / TB, TB, 0, stream>>>(x, W_s, W_f, b_f, deg,
                                                        dinv, dinvf, xw_s, sf);
    score_edge_kernel<<<gE, TB, 0, stream>>>(src, dst, dinv, xw_s, score_sd);

    gemm_xw_kernel<<<(N_NODES + 127) / 128, TB, 0, stream>>>(x, W_fu, xw);

    topk_kernel<<<NGRAPH, 512, 0, stream>>>(score_sd, dinv, xw_s, sf, b_s, batch,
                                            perm, nodemap, scoref_sel, out, o2, o3);

    edge_scan_kernel<<<NBE, 1024, 0, stream>>>(src, dst, nodemap, epos, bsumsE);
    scan_sums2_kernel<<<2, 1024, 0, stream>>>(bsumsE, bsumsN);
    scatter_csr_kernel<<<gE, TB, 0, stream>>>(src, dst, nodemap, epos, bsumsE,
                                              rowoff, bsumsN, dinvf, cursor, csr, out + o1, M);

    fuse_gather_kernel<<<(NGRAPH * KSEL * 64) / TB, TB, 0, stream>>>(
        xw, perm, rowoff, bsumsN, deg, csr, dinvf, scoref_sel, b_fu, out, o4);
}

// Round 5
// 245.434 us; speedup vs baseline: 1.9718x; 1.1140x over previous
//
#include <hip/hip_runtime.h>
#include <math.h>

#define N_NODES 50000
#define N_EDGES 500000
#define DIM     128
#define NGRAPH  50
#define NPGC    1000
#define KSEL    500
#define SORT_N  1024
#define NBE     489   // ceil(N_EDGES / 1024)
#define NBN     49    // ceil(N_NODES / 1024)
#define GEMM_BLKS 391 // ceil(N_NODES / 128)
#define DEG_BLKS  1954
#define DOTS_BLKS 12500
#define GATH_BLKS 6250

// =============== K1: gemm (xw = x @ W_fu) || deg count ===============
// gemm blocks [0,391): 128 nodes x 128 ch per block, W-half + x-tile in 64KB LDS
// (XOR-swizzled x cols). deg blocks [391, 391+1954): 1 edge/thread atomics.

__global__ __launch_bounds__(256) void k1_gemm_deg(const float* __restrict__ x,
                                                   const float* __restrict__ W,
                                                   float* __restrict__ xw,
                                                   const int* __restrict__ dst,
                                                   int* __restrict__ deg) {
    __shared__ float lds[16384];            // 64 KB
    int t = threadIdx.x;
    if (blockIdx.x >= GEMM_BLKS) {
        int e = (blockIdx.x - GEMM_BLKS) * 256 + t;
        if (e < N_EDGES) atomicAdd(&deg[dst[e]], 1);
        return;
    }
    float* Wt = lds;                        // [k][ch], 64*128
    float* Xt = lds + 64 * DIM;             // [node][k-half], swizzled, 128*64
    int cg = t & 15;
    int ng = t >> 4;
    int node_base = blockIdx.x * 128;

    float4 acc[8][2];
    #pragma unroll
    for (int nn = 0; nn < 8; nn++) {
        acc[nn][0] = make_float4(0.f, 0.f, 0.f, 0.f);
        acc[nn][1] = make_float4(0.f, 0.f, 0.f, 0.f);
    }
    for (int half = 0; half < 2; half++) {
        const float4* Wg = (const float4*)(W + half * 64 * DIM);
        float4* Wl = (float4*)Wt;
        #pragma unroll
        for (int i = 0; i < 8; i++) {
            int f = t + i * 256;
            Wl[f] = Wg[f];
        }
        #pragma unroll
        for (int i = 0; i < 8; i++) {
            int f = t + i * 256;
            int row = f >> 4, col = f & 15;
            int node = node_base + row;
            float4 v = make_float4(0.f, 0.f, 0.f, 0.f);
            if (node < N_NODES) v = *(const float4*)&x[(size_t)node * DIM + half * 64 + col * 4];
            *(float4*)&Xt[(row << 6) + ((col ^ (row & 15)) << 2)] = v;
        }
        __syncthreads();
        #pragma unroll 2
        for (int kc = 0; kc < 16; kc++) {
            int k = kc << 2;
            float4 wa[4], wb[4];
            #pragma unroll
            for (int kk = 0; kk < 4; kk++) {
                wa[kk] = *(const float4*)&Wt[(k + kk) * DIM + (cg << 2)];
                wb[kk] = *(const float4*)&Wt[(k + kk) * DIM + (cg << 2) + 64];
            }
            int csw = (kc ^ ng) << 2;
            #pragma unroll
            for (int nn = 0; nn < 8; nn++) {
                float4 xv = *(const float4*)&Xt[((ng + (nn << 4)) << 6) + csw];
                acc[nn][0].x += xv.x * wa[0].x + xv.y * wa[1].x + xv.z * wa[2].x + xv.w * wa[3].x;
                acc[nn][0].y += xv.x * wa[0].y + xv.y * wa[1].y + xv.z * wa[2].y + xv.w * wa[3].y;
                acc[nn][0].z += xv.x * wa[0].z + xv.y * wa[1].z + xv.z * wa[2].z + xv.w * wa[3].z;
                acc[nn][0].w += xv.x * wa[0].w + xv.y * wa[1].w + xv.z * wa[2].w + xv.w * wa[3].w;
                acc[nn][1].x += xv.x * wb[0].x + xv.y * wb[1].x + xv.z * wb[2].x + xv.w * wb[3].x;
                acc[nn][1].y += xv.x * wb[0].y + xv.y * wb[1].y + xv.z * wb[2].y + xv.w * wb[3].y;
                acc[nn][1].z += xv.x * wb[0].z + xv.y * wb[1].z + xv.z * wb[2].z + xv.w * wb[3].z;
                acc[nn][1].w += xv.x * wb[0].w + xv.y * wb[1].w + xv.z * wb[2].w + xv.w * wb[3].w;
            }
        }
        __syncthreads();
    }
    #pragma unroll
    for (int nn = 0; nn < 8; nn++) {
        int node = node_base + ng + (nn << 4);
        if (node < N_NODES) {
            *(float4*)&xw[(size_t)node * DIM + (cg << 2)]      = acc[nn][0];
            *(float4*)&xw[(size_t)node * DIM + (cg << 2) + 64] = acc[nn][1];
        }
    }
}

// =============== K2: rowoff block-scan || dots (dinv + x.W_s + x.W_f) ===============
// scan blocks [0,49): 256 thr x 4 deg values -> rowoff (excl within 1024-chunk) + bsumsN.
// dots blocks [49, 49+12500): 4 waves/block, one wave per node, f64 ranking path.

__global__ __launch_bounds__(256) void k2_scan_dots(const int* __restrict__ deg,
                                                    int* __restrict__ rowoff,
                                                    int* __restrict__ bsumsN,
                                                    const float* __restrict__ x,
                                                    const float* __restrict__ Ws,
                                                    const float* __restrict__ Wf,
                                                    const float* __restrict__ bf,
                                                    double* __restrict__ dinv,
                                                    float* __restrict__ dinvf,
                                                    double* __restrict__ xw_s,
                                                    double* __restrict__ sf) {
    int t = threadIdx.x;
    int lane = t & 63, wid = t >> 6;
    if (blockIdx.x < NBN) {
        __shared__ int ws4[4];
        int base = blockIdx.x * 1024 + t * 4;
        int v0 = (base + 0 < N_NODES) ? deg[base + 0] : 0;
        int v1 = (base + 1 < N_NODES) ? deg[base + 1] : 0;
        int v2 = (base + 2 < N_NODES) ? deg[base + 2] : 0;
        int v3 = (base + 3 < N_NODES) ? deg[base + 3] : 0;
        int s4 = v0 + v1 + v2 + v3;
        int incl = s4;
        #pragma unroll
        for (int off = 1; off < 64; off <<= 1) {
            int u = __shfl_up(incl, off, 64);
            if (lane >= off) incl += u;
        }
        if (lane == 63) ws4[wid] = incl;
        __syncthreads();
        int woff = 0;
        #pragma unroll
        for (int w = 0; w < 4; w++) if (w < wid) woff += ws4[w];
        int excl = incl - s4 + woff;
        if (base + 0 < N_NODES) rowoff[base + 0] = excl;
        if (base + 1 < N_NODES) rowoff[base + 1] = excl + v0;
        if (base + 2 < N_NODES) rowoff[base + 2] = excl + v0 + v1;
        if (base + 3 < N_NODES) rowoff[base + 3] = excl + v0 + v1 + v2;
        if (t == 255) bsumsN[blockIdx.x] = woff + incl;
        return;
    }
    int node = (blockIdx.x - NBN) * 4 + wid;     // exactly 50000
    const float* xr = x + (size_t)node * DIM;
    double x1 = (double)xr[lane], x2 = (double)xr[lane + 64];
    double ps = x1 * (double)Ws[lane] + x2 * (double)Ws[lane + 64];
    double pf = x1 * (double)Wf[lane] + x2 * (double)Wf[lane + 64];
    for (int off = 32; off > 0; off >>= 1) {
        ps += __shfl_down(ps, off, 64);
        pf += __shfl_down(pf, off, 64);
    }
    if (lane == 0) {
        double di = 1.0 / sqrt((double)(deg[node] + 1));
        xw_s[node]  = ps;
        sf[node]    = pf + (double)bf[0];
        dinv[node]  = di;
        dinvf[node] = (float)di;
    }
}

// =============== K3: score_edge (f64 atomics) + CSR fill, fused edge pass ===============

__global__ __launch_bounds__(256) void k3_score_csr(const int* __restrict__ src,
                                                    const int* __restrict__ dst,
                                                    const double* __restrict__ dinv,
                                                    const double* __restrict__ xw_s,
                                                    double* __restrict__ score_sd,
                                                    const int* __restrict__ rowoff,
                                                    const int* __restrict__ bsumsN,
                                                    const float* __restrict__ dinvf,
                                                    int* __restrict__ cursor,
                                                    int2* __restrict__ csr) {
    __shared__ int bsN[64];
    int t = threadIdx.x;
    if (t < 64) {                               // one wave: scan 49 block sums -> exclusive
        int v = (t < NBN) ? bsumsN[t] : 0;
        int incl = v;
        #pragma unroll
        for (int off = 1; off < 64; off <<= 1) {
            int u = __shfl_up(incl, off, 64);
            if (t >= off) incl += u;
        }
        bsN[t] = incl - v;
    }
    __syncthreads();
    int e = blockIdx.x * 256 + t;
    if (e >= N_EDGES) return;
    int s = src[e], d = dst[e];
    atomicAdd(&score_sd[d], dinv[s] * dinv[d] * xw_s[s]);
    int pos = rowoff[d] + bsN[d >> 10] + atomicAdd(&cursor[d], 1);
    csr[pos] = make_int2(s, __float_as_int(dinvf[s] * dinvf[d]));
}

// =============== K4: per-graph top-k (tanh finalize + bitonic, f64 keys) ===============

__global__ __launch_bounds__(512) void k4_topk(const double* __restrict__ score_sd,
                                               const double* __restrict__ dinv,
                                               const double* __restrict__ xw_s,
                                               const double* __restrict__ sf,
                                               const float* __restrict__ bs,
                                               const int* __restrict__ batch,
                                               int* __restrict__ perm, int* __restrict__ nodemap,
                                               float* __restrict__ scoref_sel,
                                               float* __restrict__ out, long o2, long o3) {
    __shared__ double key[SORT_N];
    __shared__ int    idx[SORT_N];
    int g = blockIdx.x, t = threadIdx.x;
    const double A = 0.6, OMA = 1.0 - 0.6;
    double bsv = (double)bs[0];
    for (int i = t; i < SORT_N; i += 512) {
        if (i < NPGC) {
            int node = g * NPGC + i;
            double di  = dinv[node];
            double tot = score_sd[node] + di * di * xw_s[node] + bsv;
            key[i] = tanh(A * tot + OMA * sf[node]);
            idx[i] = i;
        } else { key[i] = -1e300; idx[i] = i; }
    }
    __syncthreads();
    for (int size = 2; size <= SORT_N; size <<= 1) {
        for (int stride = size >> 1; stride > 0; stride >>= 1) {
            int a = ((t & ~(stride - 1)) << 1) | (t & (stride - 1));
            int b = a | stride;
            bool descFirst = ((a & size) == 0);
            double ka = key[a], kb = key[b];
            int ia = idx[a], ib = idx[b];
            bool aAfterB = (ka < kb) || (ka == kb && ia > ib);  // stable descending
            if (descFirst ? aAfterB : !aAfterB) {
                key[a] = kb; key[b] = ka;
                idx[a] = ib; idx[b] = ia;
            }
            __syncthreads();
        }
    }
    for (int j = t; j < KSEL; j += 512) {
        int node = g * NPGC + idx[j];
        int pos  = g * KSEL + j;
        perm[pos]        = node;
        nodemap[node]    = pos + 1;             // 0 = unselected
        scoref_sel[pos]  = (float)key[j];
        out[o2 + pos]    = (float)batch[node];  // batch_out
        out[o3 + pos]    = (float)node;         // perm
    }
}

// =============== K5: edge flag+scan || fusion gather ===============
// scan blocks [0,489): 256 thr x 4 edges -> epos (excl within 1024-chunk) + bsumsE.
// gather blocks [489, 489+6250): one wave per selected node, CSR loop, 2-way ILP.

__global__ __launch_bounds__(256) void k5_escan_gather(const int* __restrict__ src,
                                                       const int* __restrict__ dst,
                                                       const int* __restrict__ nodemap,
                                                       int* __restrict__ epos,
                                                       int* __restrict__ bsumsE,
                                                       const float* __restrict__ xw,
                                                       const int* __restrict__ perm,
                                                       const int* __restrict__ rowoff,
                                                       const int* __restrict__ bsumsN,
                                                       const int* __restrict__ deg,
                                                       const int2* __restrict__ csr,
                                                       const float* __restrict__ dinvf,
                                                       const float* __restrict__ scoref_sel,
                                                       const float* __restrict__ b_fu,
                                                       float* __restrict__ out, long o4) {
    int t = threadIdx.x;
    int lane = t & 63, wid = t >> 6;
    if (blockIdx.x < NBE) {
        __shared__ int ws4[4];
        int base = blockIdx.x * 1024 + t * 4;
        int v0 = 0, v1 = 0, v2 = 0, v3 = 0;
        if (base + 0 < N_EDGES) v0 = (nodemap[src[base + 0]] > 0 && nodemap[dst[base + 0]] > 0);
        if (base + 1 < N_EDGES) v1 = (nodemap[src[base + 1]] > 0 && nodemap[dst[base + 1]] > 0);
        if (base + 2 < N_EDGES) v2 = (nodemap[src[base + 2]] > 0 && nodemap[dst[base + 2]] > 0);
        if (base + 3 < N_EDGES) v3 = (nodemap[src[base + 3]] > 0 && nodemap[dst[base + 3]] > 0);
        int s4 = v0 + v1 + v2 + v3;
        int incl = s4;
        #pragma unroll
        for (int off = 1; off < 64; off <<= 1) {
            int u = __shfl_up(incl, off, 64);
            if (lane >= off) incl += u;
        }
        if (lane == 63) ws4[wid] = incl;
        __syncthreads();
        int woff = 0;
        #pragma unroll
        for (int w = 0; w < 4; w++) if (w < wid) woff += ws4[w];
        int excl = incl - s4 + woff;
        if (base + 0 < N_EDGES) epos[base + 0] = excl;
        if (base + 1 < N_EDGES) epos[base + 1] = excl + v0;
        if (base + 2 < N_EDGES) epos[base + 2] = excl + v0 + v1;
        if (base + 3 < N_EDGES) epos[base + 3] = excl + v0 + v1 + v2;
        if (t == 255) bsumsE[blockIdx.x] = woff + incl;
        return;
    }
    __shared__ int bsN[64];
    if (t < 64) {
        int v = (t < NBN) ? bsumsN[t] : 0;
        int incl = v;
        #pragma unroll
        for (int off = 1; off < 64; off <<= 1) {
            int u = __shfl_up(incl, off, 64);
            if (t >= off) incl += u;
        }
        bsN[t] = incl - v;
    }
    __syncthreads();
    int wave = (blockIdx.x - NBE) * 4 + wid;     // exactly 25000
    int p = perm[wave];
    float dpf = dinvf[p];
    int c2 = lane * 2;
    float2 v = ((const float2*)(xw + (size_t)p * DIM))[lane];
    float nself = dpf * dpf;
    float ax = nself * v.x, ay = nself * v.y;
    int beg = rowoff[p] + bsN[p >> 10], cnt = deg[p];
    int i = 0;
    for (; i + 2 <= cnt; i += 2) {
        int2 e0 = csr[beg + i];
        int2 e1 = csr[beg + i + 1];
        float2 u0 = ((const float2*)(xw + (size_t)e0.x * DIM))[lane];
        float2 u1 = ((const float2*)(xw + (size_t)e1.x * DIM))[lane];
        float n0 = __int_as_float(e0.y), n1 = __int_as_float(e1.y);
        ax += n0 * u0.x; ay += n0 * u0.y;
        ax += n1 * u1.x; ay += n1 * u1.y;
    }
    if (i < cnt) {
        int2 e0 = csr[beg + i];
        float2 u0 = ((const float2*)(xw + (size_t)e0.x * DIM))[lane];
        float n0 = __int_as_float(e0.y);
        ax += n0 * u0.x; ay += n0 * u0.y;
    }
    ax += b_fu[c2];
    ay += b_fu[c2 + 1];
    float sc = scoref_sel[wave];
    size_t ro = (size_t)wave * DIM + c2;
    out[o4 + ro]     = ax;        // x_ae
    out[o4 + ro + 1] = ay;
    out[ro]          = ax * sc;   // x_out
    out[ro + 1]      = ay * sc;
}

// =============== K6: edge compaction scatter (remap + write) ===============
// per block: one wave scans the 489 bsumsE entries into LDS, then 1 edge/thread.

__global__ __launch_bounds__(256) void k6_compact(const int* __restrict__ src,
                                                  const int* __restrict__ dst,
                                                  const int* __restrict__ nodemap,
                                                  const int* __restrict__ epos,
                                                  const int* __restrict__ bsumsE,
                                                  float* __restrict__ out_edges, long M) {
    __shared__ int bsE[512];
    int t = threadIdx.x;
    if (t < 64) {                               // wave 0: scan 489 entries, 8 chunks of 64
        int carry = 0;
        #pragma unroll
        for (int c = 0; c < 8; c++) {
            int i = c * 64 + t;
            int v = (i < NBE) ? bsumsE[i] : 0;
            int incl = v;
            #pragma unroll
            for (int off = 1; off < 64; off <<= 1) {
                int u = __shfl_up(incl, off, 64);
                if (t >= off) incl += u;
            }
            if (i < 512) bsE[i] = incl - v + carry;
            carry += __shfl(incl, 63, 64);
        }
    }
    __syncthreads();
    int e = blockIdx.x * 256 + t;
    if (e >= N_EDGES) return;
    int r = nodemap[src[e]], c = nodemap[dst[e]];
    if (r > 0 && c > 0) {
        int pos = epos[e] + bsE[e >> 10];
        out_edges[pos]     = (float)(r - 1);
        out_edges[M + pos] = (float)(c - 1);
    }
}

// ---------------- host ----------------

extern "C" void kernel_launch(void* const* d_in, const int* in_sizes, int n_in,
                              void* d_out, int out_size, void* d_ws, size_t ws_size,
                              hipStream_t stream) {
    const float* x    = (const float*)d_in[0];
    const int*   ei   = (const int*)d_in[1];
    const int*   src  = ei;
    const int*   dst  = ei + N_EDGES;
    const int*   batch= (const int*)d_in[2];
    const float* W_s  = (const float*)d_in[3];
    const float* b_s  = (const float*)d_in[4];
    const float* W_f  = (const float*)d_in[5];
    const float* b_f  = (const float*)d_in[6];
    const float* W_fu = (const float*)d_in[7];
    const float* b_fu = (const float*)d_in[8];
    float* out = (float*)d_out;

    char* wsp = (char*)d_ws;
    size_t off = 0;
    auto take = [&](size_t bytes) -> char* {
        char* p = wsp + off;
        off = (off + bytes + 255) & ~(size_t)255;
        return p;
    };
    // zero-cluster (single memset): score_sd | deg | cursor | nodemap (0 = unselected)
    char*   zbase      = wsp;
    double* score_sd   = (double*)take((size_t)N_NODES * 8);
    int*    deg        = (int*)   take((size_t)N_NODES * 4);
    int*    cursor     = (int*)   take((size_t)N_NODES * 4);
    int*    nodemap    = (int*)   take((size_t)N_NODES * 4);
    size_t  zbytes     = off;
    double* dinv       = (double*)take((size_t)N_NODES * 8);
    double* xw_s       = (double*)take((size_t)N_NODES * 8);
    double* sf         = (double*)take((size_t)N_NODES * 8);
    float*  dinvf      = (float*) take((size_t)N_NODES * 4);
    float*  scoref_sel = (float*) take((size_t)NGRAPH * KSEL * 4);
    int*    perm       = (int*)   take((size_t)NGRAPH * KSEL * 4);
    int*    rowoff     = (int*)   take((size_t)N_NODES * 4);
    int*    epos       = (int*)   take((size_t)N_EDGES * 4);
    int*    bsumsE     = (int*)   take((size_t)1024 * 4);
    int*    bsumsN     = (int*)   take((size_t)1024 * 4);
    int2*   csr        = (int2*)  take((size_t)N_EDGES * 8);
    float*  xw         = (float*) take((size_t)N_NODES * DIM * 4);

    // output layout: x_out[25000*128] | edge_index_new[2*M] | batch_out | perm | x_ae[25000*128]
    long M  = ((long)out_size - 6450000L) / 2;
    long o1 = 3200000L;
    long o2 = o1 + 2 * M;
    long o3 = o2 + (long)NGRAPH * KSEL;
    long o4 = o3 + (long)NGRAPH * KSEL;

    hipMemsetAsync(zbase, 0, zbytes, stream);

    k1_gemm_deg<<<GEMM_BLKS + DEG_BLKS, 256, 0, stream>>>(x, W_fu, xw, dst, deg);
    k2_scan_dots<<<NBN + DOTS_BLKS, 256, 0, stream>>>(deg, rowoff, bsumsN,
                                                      x, W_s, W_f, b_f,
                                                      dinv, dinvf, xw_s, sf);
    k3_score_csr<<<DEG_BLKS, 256, 0, stream>>>(src, dst, dinv, xw_s, score_sd,
                                               rowoff, bsumsN, dinvf, cursor, csr);
    k4_topk<<<NGRAPH, 512, 0, stream>>>(score_sd, dinv, xw_s, sf, b_s, batch,
                                        perm, nodemap, scoref_sel, out, o2, o3);
    k5_escan_gather<<<NBE + GATH_BLKS, 256, 0, stream>>>(src, dst, nodemap, epos, bsumsE,
                                                         xw, perm, rowoff, bsumsN, deg, csr,
                                                         dinvf, scoref_sel, b_fu, out, o4);
    k6_compact<<<DEG_BLKS, 256, 0, stream>>>(src, dst, nodemap, epos, bsumsE, out + o1, M);
}

// Round 6
// 228.301 us; speedup vs baseline: 2.1198x; 1.0750x over previous
//
#include <hip/hip_runtime.h>
#include <math.h>

#define N_NODES 50000
#define N_EDGES 500000
#define DIM     128
#define NGRAPH  50
#define NPGC    1000
#define KSEL    500
#define SORT_N  1024
#define NBE     489    // ceil(N_EDGES / 1024)
#define NBN     49     // ceil(N_NODES / 1024)
#define GEMM_BLKS 391  // ceil(N_NODES / 128)
#define DEG_BLKS  1954 // ceil(N_EDGES / 256)
#define DOTS_BLKS 12500
#define NDINV     196  // ceil(N_NODES / 256)
#define GATH_BLKS 6250

// =============== K1: gemm (xw = x @ W_fu) || deg count ===============
// gemm blocks [0,391): 128 nodes x 128 ch per block, W-half + x-tile in 64KB LDS
// (XOR-swizzled x cols). deg blocks [391, 391+1954): 1 edge/thread atomics.

__global__ __launch_bounds__(256) void k1_gemm_deg(const float* __restrict__ x,
                                                   const float* __restrict__ W,
                                                   float* __restrict__ xw,
                                                   const int* __restrict__ dst,
                                                   int* __restrict__ deg) {
    __shared__ float lds[16384];            // 64 KB
    int t = threadIdx.x;
    if (blockIdx.x >= GEMM_BLKS) {
        int e = (blockIdx.x - GEMM_BLKS) * 256 + t;
        if (e < N_EDGES) atomicAdd(&deg[dst[e]], 1);
        return;
    }
    float* Wt = lds;                        // [k][ch], 64*128
    float* Xt = lds + 64 * DIM;             // [node][k-half], swizzled, 128*64
    int cg = t & 15;
    int ng = t >> 4;
    int node_base = blockIdx.x * 128;

    float4 acc[8][2];
    #pragma unroll
    for (int nn = 0; nn < 8; nn++) {
        acc[nn][0] = make_float4(0.f, 0.f, 0.f, 0.f);
        acc[nn][1] = make_float4(0.f, 0.f, 0.f, 0.f);
    }
    for (int half = 0; half < 2; half++) {
        const float4* Wg = (const float4*)(W + half * 64 * DIM);
        float4* Wl = (float4*)Wt;
        #pragma unroll
        for (int i = 0; i < 8; i++) {
            int f = t + i * 256;
            Wl[f] = Wg[f];
        }
        #pragma unroll
        for (int i = 0; i < 8; i++) {
            int f = t + i * 256;
            int row = f >> 4, col = f & 15;
            int node = node_base + row;
            float4 v = make_float4(0.f, 0.f, 0.f, 0.f);
            if (node < N_NODES) v = *(const float4*)&x[(size_t)node * DIM + half * 64 + col * 4];
            *(float4*)&Xt[(row << 6) + ((col ^ (row & 15)) << 2)] = v;
        }
        __syncthreads();
        #pragma unroll 2
        for (int kc = 0; kc < 16; kc++) {
            int k = kc << 2;
            float4 wa[4], wb[4];
            #pragma unroll
            for (int kk = 0; kk < 4; kk++) {
                wa[kk] = *(const float4*)&Wt[(k + kk) * DIM + (cg << 2)];
                wb[kk] = *(const float4*)&Wt[(k + kk) * DIM + (cg << 2) + 64];
            }
            int csw = (kc ^ ng) << 2;
            #pragma unroll
            for (int nn = 0; nn < 8; nn++) {
                float4 xv = *(const float4*)&Xt[((ng + (nn << 4)) << 6) + csw];
                acc[nn][0].x += xv.x * wa[0].x + xv.y * wa[1].x + xv.z * wa[2].x + xv.w * wa[3].x;
                acc[nn][0].y += xv.x * wa[0].y + xv.y * wa[1].y + xv.z * wa[2].y + xv.w * wa[3].y;
                acc[nn][0].z += xv.x * wa[0].z + xv.y * wa[1].z + xv.z * wa[2].z + xv.w * wa[3].z;
                acc[nn][0].w += xv.x * wa[0].w + xv.y * wa[1].w + xv.z * wa[2].w + xv.w * wa[3].w;
                acc[nn][1].x += xv.x * wb[0].x + xv.y * wb[1].x + xv.z * wb[2].x + xv.w * wb[3].x;
                acc[nn][1].y += xv.x * wb[0].y + xv.y * wb[1].y + xv.z * wb[2].y + xv.w * wb[3].y;
                acc[nn][1].z += xv.x * wb[0].z + xv.y * wb[1].z + xv.z * wb[2].z + xv.w * wb[3].z;
                acc[nn][1].w += xv.x * wb[0].w + xv.y * wb[1].w + xv.z * wb[2].w + xv.w * wb[3].w;
            }
        }
        __syncthreads();
    }
    #pragma unroll
    for (int nn = 0; nn < 8; nn++) {
        int node = node_base + ng + (nn << 4);
        if (node < N_NODES) {
            *(float4*)&xw[(size_t)node * DIM + (cg << 2)]      = acc[nn][0];
            *(float4*)&xw[(size_t)node * DIM + (cg << 2) + 64] = acc[nn][1];
        }
    }
}

// =============== K2: dots || rowoff block-scan || dinv ===============
// dots blocks [0,12500): one wave per node, f64 x.W_s / x.W_f; writes pack[2i+1]=xw_s, sf.
// scan blocks [12500,12549): 256 thr x 4 deg -> rowoff excl-within-1024 + bsumsN.
// dinv blocks [12549,12745): pack[2i]=dinv (f64), dinvf (f32).

__global__ __launch_bounds__(256) void k2_dots_scan_dinv(const int* __restrict__ deg,
                                                         int* __restrict__ rowoff,
                                                         int* __restrict__ bsumsN,
                                                         const float* __restrict__ x,
                                                         const float* __restrict__ Ws,
                                                         const float* __restrict__ Wf,
                                                         const float* __restrict__ bf,
                                                         double* __restrict__ pack,
                                                         float* __restrict__ dinvf,
                                                         double* __restrict__ sf) {
    int t = threadIdx.x;
    int lane = t & 63, wid = t >> 6;
    int bid = blockIdx.x;
    if (bid < DOTS_BLKS) {
        int node = bid * 4 + wid;                // exactly 50000
        const float* xr = x + (size_t)node * DIM;
        double x1 = (double)xr[lane], x2 = (double)xr[lane + 64];
        double ps = x1 * (double)Ws[lane] + x2 * (double)Ws[lane + 64];
        double pf = x1 * (double)Wf[lane] + x2 * (double)Wf[lane + 64];
        for (int off = 32; off > 0; off >>= 1) {
            ps += __shfl_down(ps, off, 64);
            pf += __shfl_down(pf, off, 64);
        }
        if (lane == 0) {
            pack[2 * node + 1] = ps;             // xw_s
            sf[node] = pf + (double)bf[0];
        }
        return;
    }
    if (bid < DOTS_BLKS + NBN) {
        __shared__ int ws4[4];
        int base = (bid - DOTS_BLKS) * 1024 + t * 4;
        int v0 = (base + 0 < N_NODES) ? deg[base + 0] : 0;
        int v1 = (base + 1 < N_NODES) ? deg[base + 1] : 0;
        int v2 = (base + 2 < N_NODES) ? deg[base + 2] : 0;
        int v3 = (base + 3 < N_NODES) ? deg[base + 3] : 0;
        int s4 = v0 + v1 + v2 + v3;
        int incl = s4;
        #pragma unroll
        for (int off = 1; off < 64; off <<= 1) {
            int u = __shfl_up(incl, off, 64);
            if (lane >= off) incl += u;
        }
        if (lane == 63) ws4[wid] = incl;
        __syncthreads();
        int woff = 0;
        #pragma unroll
        for (int w = 0; w < 4; w++) if (w < wid) woff += ws4[w];
        int excl = incl - s4 + woff;
        if (base + 0 < N_NODES) rowoff[base + 0] = excl;
        if (base + 1 < N_NODES) rowoff[base + 1] = excl + v0;
        if (base + 2 < N_NODES) rowoff[base + 2] = excl + v0 + v1;
        if (base + 3 < N_NODES) rowoff[base + 3] = excl + v0 + v1 + v2;
        if (t == 255) bsumsN[bid - DOTS_BLKS] = woff + incl;
        return;
    }
    int i = (bid - DOTS_BLKS - NBN) * 256 + t;
    if (i < N_NODES) {
        double di = 1.0 / sqrt((double)(deg[i] + 1));
        pack[2 * i] = di;
        dinvf[i] = (float)di;
    }
}

// =============== K3: CSR fill only (cursor atomics; payload = src id, 4B) ===============

__global__ __launch_bounds__(256) void k3_csr(const int* __restrict__ src,
                                              const int* __restrict__ dst,
                                              const int* __restrict__ rowoff,
                                              const int* __restrict__ bsumsN,
                                              int* __restrict__ cursor,
                                              int* __restrict__ csr) {
    __shared__ int bsN[64];
    int t = threadIdx.x;
    if (t < 64) {                               // one wave: scan 49 block sums -> exclusive
        int v = (t < NBN) ? bsumsN[t] : 0;
        int incl = v;
        #pragma unroll
        for (int off = 1; off < 64; off <<= 1) {
            int u = __shfl_up(incl, off, 64);
            if (t >= off) incl += u;
        }
        bsN[t] = incl - v;
    }
    __syncthreads();
    int e = blockIdx.x * 256 + t;
    if (e >= N_EDGES) return;
    int d = dst[e];
    int pos = rowoff[d] + bsN[d >> 10] + atomicAdd(&cursor[d], 1);
    csr[pos] = src[e];
}

// =============== K3b: structure score via CSR gather (no atomics, f64) ===============
// score_sd[d] = dinv[d] * sum_{s in in(d)} dinv[s]*xw_s[s]; one thread per node.

__global__ __launch_bounds__(256) void k3b_score(const int* __restrict__ csr,
                                                 const int* __restrict__ rowoff,
                                                 const int* __restrict__ bsumsN,
                                                 const int* __restrict__ deg,
                                                 const double* __restrict__ pack,
                                                 double* __restrict__ score_sd) {
    __shared__ int bsN[64];
    int t = threadIdx.x;
    if (t < 64) {
        int v = (t < NBN) ? bsumsN[t] : 0;
        int incl = v;
        #pragma unroll
        for (int off = 1; off < 64; off <<= 1) {
            int u = __shfl_up(incl, off, 64);
            if (t >= off) incl += u;
        }
        bsN[t] = incl - v;
    }
    __syncthreads();
    int node = blockIdx.x * 256 + t;
    if (node >= N_NODES) return;
    int base = rowoff[node] + bsN[node >> 10];
    int cnt  = deg[node];
    double acc0 = 0.0, acc1 = 0.0;
    int i = 0;
    for (; i + 2 <= cnt; i += 2) {
        int s0 = csr[base + i];
        int s1 = csr[base + i + 1];
        double2 p0 = ((const double2*)pack)[s0];   // {dinv, xw_s}
        double2 p1 = ((const double2*)pack)[s1];
        acc0 += p0.x * p0.y;
        acc1 += p1.x * p1.y;
    }
    if (i < cnt) {
        int s0 = csr[base + i];
        double2 p0 = ((const double2*)pack)[s0];
        acc0 += p0.x * p0.y;
    }
    score_sd[node] = pack[2 * node] * (acc0 + acc1);
}

// =============== K4: per-graph top-k (tanh finalize + bitonic, f64 keys) ===============

__global__ __launch_bounds__(512) void k4_topk(const double* __restrict__ score_sd,
                                               const double* __restrict__ pack,
                                               const double* __restrict__ sf,
                                               const float* __restrict__ bs,
                                               const int* __restrict__ batch,
                                               int* __restrict__ perm, int* __restrict__ nodemap,
                                               float* __restrict__ scoref_sel,
                                               float* __restrict__ out, long o2, long o3) {
    __shared__ double key[SORT_N];
    __shared__ int    idx[SORT_N];
    int g = blockIdx.x, t = threadIdx.x;
    const double A = 0.6, OMA = 1.0 - 0.6;
    double bsv = (double)bs[0];
    for (int i = t; i < SORT_N; i += 512) {
        if (i < NPGC) {
            int node = g * NPGC + i;
            double2 p = ((const double2*)pack)[node];   // {dinv, xw_s}
            double tot = score_sd[node] + p.x * p.x * p.y + bsv;  // + self loop + b_s
            key[i] = tanh(A * tot + OMA * sf[node]);
            idx[i] = i;
        } else { key[i] = -1e300; idx[i] = i; }
    }
    __syncthreads();
    for (int size = 2; size <= SORT_N; size <<= 1) {
        for (int stride = size >> 1; stride > 0; stride >>= 1) {
            int a = ((t & ~(stride - 1)) << 1) | (t & (stride - 1));
            int b = a | stride;
            bool descFirst = ((a & size) == 0);
            double ka = key[a], kb = key[b];
            int ia = idx[a], ib = idx[b];
            bool aAfterB = (ka < kb) || (ka == kb && ia > ib);  // stable descending
            if (descFirst ? aAfterB : !aAfterB) {
                key[a] = kb; key[b] = ka;
                idx[a] = ib; idx[b] = ia;
            }
            __syncthreads();
        }
    }
    for (int j = t; j < KSEL; j += 512) {
        int node = g * NPGC + idx[j];
        int pos  = g * KSEL + j;
        perm[pos]        = node;
        nodemap[node]    = pos + 1;             // 0 = unselected
        scoref_sel[pos]  = (float)key[j];
        out[o2 + pos]    = (float)batch[node];  // batch_out
        out[o3 + pos]    = (float)node;         // perm
    }
}

// =============== K5: edge flag+scan || fusion gather ===============

__global__ __launch_bounds__(256) void k5_escan_gather(const int* __restrict__ src,
                                                       const int* __restrict__ dst,
                                                       const int* __restrict__ nodemap,
                                                       int* __restrict__ epos,
                                                       int* __restrict__ bsumsE,
                                                       const float* __restrict__ xw,
                                                       const int* __restrict__ perm,
                                                       const int* __restrict__ rowoff,
                                                       const int* __restrict__ bsumsN,
                                                       const int* __restrict__ deg,
                                                       const int* __restrict__ csr,
                                                       const float* __restrict__ dinvf,
                                                       const float* __restrict__ scoref_sel,
                                                       const float* __restrict__ b_fu,
                                                       float* __restrict__ out, long o4) {
    int t = threadIdx.x;
    int lane = t & 63, wid = t >> 6;
    if (blockIdx.x < NBE) {
        __shared__ int ws4[4];
        int base = blockIdx.x * 1024 + t * 4;
        int v0 = 0, v1 = 0, v2 = 0, v3 = 0;
        if (base + 0 < N_EDGES) v0 = (nodemap[src[base + 0]] > 0 && nodemap[dst[base + 0]] > 0);
        if (base + 1 < N_EDGES) v1 = (nodemap[src[base + 1]] > 0 && nodemap[dst[base + 1]] > 0);
        if (base + 2 < N_EDGES) v2 = (nodemap[src[base + 2]] > 0 && nodemap[dst[base + 2]] > 0);
        if (base + 3 < N_EDGES) v3 = (nodemap[src[base + 3]] > 0 && nodemap[dst[base + 3]] > 0);
        int s4 = v0 + v1 + v2 + v3;
        int incl = s4;
        #pragma unroll
        for (int off = 1; off < 64; off <<= 1) {
            int u = __shfl_up(incl, off, 64);
            if (lane >= off) incl += u;
        }
        if (lane == 63) ws4[wid] = incl;
        __syncthreads();
        int woff = 0;
        #pragma unroll
        for (int w = 0; w < 4; w++) if (w < wid) woff += ws4[w];
        int excl = incl - s4 + woff;
        if (base + 0 < N_EDGES) epos[base + 0] = excl;
        if (base + 1 < N_EDGES) epos[base + 1] = excl + v0;
        if (base + 2 < N_EDGES) epos[base + 2] = excl + v0 + v1;
        if (base + 3 < N_EDGES) epos[base + 3] = excl + v0 + v1 + v2;
        if (t == 255) bsumsE[blockIdx.x] = woff + incl;
        return;
    }
    __shared__ int bsN[64];
    if (t < 64) {
        int v = (t < NBN) ? bsumsN[t] : 0;
        int incl = v;
        #pragma unroll
        for (int off = 1; off < 64; off <<= 1) {
            int u = __shfl_up(incl, off, 64);
            if (t >= off) incl += u;
        }
        bsN[t] = incl - v;
    }
    __syncthreads();
    int wave = (blockIdx.x - NBE) * 4 + wid;     // exactly 25000
    int p = perm[wave];
    float dpf = dinvf[p];
    int c2 = lane * 2;
    float2 v = ((const float2*)(xw + (size_t)p * DIM))[lane];
    float nself = dpf * dpf;
    float ax = nself * v.x, ay = nself * v.y;
    int beg = rowoff[p] + bsN[p >> 10], cnt = deg[p];
    int i = 0;
    for (; i + 2 <= cnt; i += 2) {
        int s0 = csr[beg + i];
        int s1 = csr[beg + i + 1];
        float2 u0 = ((const float2*)(xw + (size_t)s0 * DIM))[lane];
        float2 u1 = ((const float2*)(xw + (size_t)s1 * DIM))[lane];
        float n0 = dinvf[s0] * dpf, n1 = dinvf[s1] * dpf;
        ax += n0 * u0.x; ay += n0 * u0.y;
        ax += n1 * u1.x; ay += n1 * u1.y;
    }
    if (i < cnt) {
        int s0 = csr[beg + i];
        float2 u0 = ((const float2*)(xw + (size_t)s0 * DIM))[lane];
        float n0 = dinvf[s0] * dpf;
        ax += n0 * u0.x; ay += n0 * u0.y;
    }
    ax += b_fu[c2];
    ay += b_fu[c2 + 1];
    float sc = scoref_sel[wave];
    size_t ro = (size_t)wave * DIM + c2;
    out[o4 + ro]     = ax;        // x_ae
    out[o4 + ro + 1] = ay;
    out[ro]          = ax * sc;   // x_out
    out[ro + 1]      = ay * sc;
}

// =============== K6: edge compaction scatter (remap + write) ===============

__global__ __launch_bounds__(256) void k6_compact(const int* __restrict__ src,
                                                  const int* __restrict__ dst,
                                                  const int* __restrict__ nodemap,
                                                  const int* __restrict__ epos,
                                                  const int* __restrict__ bsumsE,
                                                  float* __restrict__ out_edges, long M) {
    __shared__ int bsE[512];
    int t = threadIdx.x;
    if (t < 64) {                               // wave 0: scan 489 entries, 8 chunks of 64
        int carry = 0;
        #pragma unroll
        for (int c = 0; c < 8; c++) {
            int i = c * 64 + t;
            int v = (i < NBE) ? bsumsE[i] : 0;
            int incl = v;
            #pragma unroll
            for (int off = 1; off < 64; off <<= 1) {
                int u = __shfl_up(incl, off, 64);
                if (t >= off) incl += u;
            }
            if (i < 512) bsE[i] = incl - v + carry;
            carry += __shfl(incl, 63, 64);
        }
    }
    __syncthreads();
    int e = blockIdx.x * 256 + t;
    if (e >= N_EDGES) return;
    int r = nodemap[src[e]], c = nodemap[dst[e]];
    if (r > 0 && c > 0) {
        int pos = epos[e] + bsE[e >> 10];
        out_edges[pos]     = (float)(r - 1);
        out_edges[M + pos] = (float)(c - 1);
    }
}

// ---------------- host ----------------

extern "C" void kernel_launch(void* const* d_in, const int* in_sizes, int n_in,
                              void* d_out, int out_size, void* d_ws, size_t ws_size,
                              hipStream_t stream) {
    const float* x    = (const float*)d_in[0];
    const int*   ei   = (const int*)d_in[1];
    const int*   src  = ei;
    const int*   dst  = ei + N_EDGES;
    const int*   batch= (const int*)d_in[2];
    const float* W_s  = (const float*)d_in[3];
    const float* b_s  = (const float*)d_in[4];
    const float* W_f  = (const float*)d_in[5];
    const float* b_f  = (const float*)d_in[6];
    const float* W_fu = (const float*)d_in[7];
    const float* b_fu = (const float*)d_in[8];
    float* out = (float*)d_out;

    char* wsp = (char*)d_ws;
    size_t off = 0;
    auto take = [&](size_t bytes) -> char* {
        char* p = wsp + off;
        off = (off + bytes + 255) & ~(size_t)255;
        return p;
    };
    // zero-cluster (single memset): deg | cursor | nodemap (0 = unselected)
    char*   zbase      = wsp;
    int*    deg        = (int*)   take((size_t)N_NODES * 4);
    int*    cursor     = (int*)   take((size_t)N_NODES * 4);
    int*    nodemap    = (int*)   take((size_t)N_NODES * 4);
    size_t  zbytes     = off;
    double* score_sd   = (double*)take((size_t)N_NODES * 8);
    double* pack       = (double*)take((size_t)N_NODES * 16);  // {dinv, xw_s} per node
    double* sf         = (double*)take((size_t)N_NODES * 8);
    float*  dinvf      = (float*) take((size_t)N_NODES * 4);
    float*  scoref_sel = (float*) take((size_t)NGRAPH * KSEL * 4);
    int*    perm       = (int*)   take((size_t)NGRAPH * KSEL * 4);
    int*    rowoff     = (int*)   take((size_t)N_NODES * 4);
    int*    epos       = (int*)   take((size_t)N_EDGES * 4);
    int*    bsumsE     = (int*)   take((size_t)1024 * 4);
    int*    bsumsN     = (int*)   take((size_t)1024 * 4);
    int*    csr        = (int*)   take((size_t)N_EDGES * 4);
    float*  xw         = (float*) take((size_t)N_NODES * DIM * 4);

    // output layout: x_out[25000*128] | edge_index_new[2*M] | batch_out | perm | x_ae[25000*128]
    long M  = ((long)out_size - 6450000L) / 2;
    long o1 = 3200000L;
    long o2 = o1 + 2 * M;
    long o3 = o2 + (long)NGRAPH * KSEL;
    long o4 = o3 + (long)NGRAPH * KSEL;

    hipMemsetAsync(zbase, 0, zbytes, stream);

    k1_gemm_deg<<<GEMM_BLKS + DEG_BLKS, 256, 0, stream>>>(x, W_fu, xw, dst, deg);
    k2_dots_scan_dinv<<<DOTS_BLKS + NBN + NDINV, 256, 0, stream>>>(deg, rowoff, bsumsN,
                                                                   x, W_s, W_f, b_f,
                                                                   pack, dinvf, sf);
    k3_csr<<<DEG_BLKS, 256, 0, stream>>>(src, dst, rowoff, bsumsN, cursor, csr);
    k3b_score<<<NDINV, 256, 0, stream>>>(csr, rowoff, bsumsN, deg, pack, score_sd);
    k4_topk<<<NGRAPH, 512, 0, stream>>>(score_sd, pack, sf, b_s, batch,
                                        perm, nodemap, scoref_sel, out, o2, o3);
    k5_escan_gather<<<NBE + GATH_BLKS, 256, 0, stream>>>(src, dst, nodemap, epos, bsumsE,
                                                         xw, perm, rowoff, bsumsN, deg, csr,
                                                         dinvf, scoref_sel, b_fu, out, o4);
    k6_compact<<<DEG_BLKS, 256, 0, stream>>>(src, dst, nodemap, epos, bsumsE, out + o1, M);
}